// Round 3
// baseline (709.753 us; speedup 1.0000x reference)
//
#include <hip/hip_runtime.h>
#include <math.h>

#define IN_DIM 32
#define HID 64
#define HEADS 4
#define OUTC 64
#define GHID (HEADS*OUTC)   // 256
#define LRELU_S 0.01f
#define GAT_S 0.2f

__device__ __forceinline__ float lrelu(float v, float s){ return v >= 0.f ? v : s*v; }

// ---------------- CSR build ----------------
__global__ void k_zero(int* __restrict__ p, int n){
    int i = blockIdx.x*256 + threadIdx.x;
    if (i < n) p[i] = 0;
}

__global__ void k_hist(const int* __restrict__ dst, int E, int* __restrict__ deg){
    int i = blockIdx.x*256 + threadIdx.x;
    if (i < E) atomicAdd(&deg[dst[i]], 1);
}

__global__ void k_scan_block(const int* __restrict__ in, int* __restrict__ out,
                             int* __restrict__ bsum, int n){
    __shared__ int s[256];
    int i = blockIdx.x*256 + threadIdx.x;
    int v = (i < n) ? in[i] : 0;
    s[threadIdx.x] = v;
    __syncthreads();
    for (int off = 1; off < 256; off <<= 1){
        int t = (threadIdx.x >= off) ? s[threadIdx.x - off] : 0;
        __syncthreads();
        s[threadIdx.x] += t;
        __syncthreads();
    }
    if (i < n) out[i] = s[threadIdx.x] - v;          // exclusive
    if (threadIdx.x == 255) bsum[blockIdx.x] = s[255];
}

__global__ void k_scan_top(int* __restrict__ bsum, int n){
    __shared__ int s[256];
    int v = (threadIdx.x < n) ? bsum[threadIdx.x] : 0;
    s[threadIdx.x] = v;
    __syncthreads();
    for (int off = 1; off < 256; off <<= 1){
        int t = (threadIdx.x >= off) ? s[threadIdx.x - off] : 0;
        __syncthreads();
        s[threadIdx.x] += t;
        __syncthreads();
    }
    if (threadIdx.x < n) bsum[threadIdx.x] = s[threadIdx.x] - v;  // exclusive
}

__global__ void k_scan_add(int* __restrict__ row, const int* __restrict__ bsum,
                           int* __restrict__ cur, int n){
    int i = blockIdx.x*256 + threadIdx.x;
    if (i < n){
        int v = row[i] + bsum[blockIdx.x];
        row[i] = v;
        cur[i] = v;
    }
}

__global__ void k_scatter(const int* __restrict__ src, const int* __restrict__ dst, int E,
                          int* __restrict__ cur, int* __restrict__ csr_src){
    int i = blockIdx.x*256 + threadIdx.x;
    if (i < E){
        int d = dst[i];
        int pos = atomicAdd(&cur[d], 1);
        csr_src[pos] = src[i];
    }
}

// ---------------- input projection: h0 = leaky(x@W_in + b_in) ----------------
__global__ __launch_bounds__(256) void k_proj(const float* __restrict__ x,
                                              const float* __restrict__ Win,
                                              const float* __restrict__ bin,
                                              float* __restrict__ h0, int n){
    __shared__ float sW[IN_DIM*HID];  // 8KB
    for (int i = threadIdx.x; i < IN_DIM*HID; i += 256) sW[i] = Win[i];
    __syncthreads();
    int gid = blockIdx.x*256 + threadIdx.x;
    int node = gid >> 6, c = gid & 63;
    if (node >= n) return;
    const float* xr = x + (size_t)node*IN_DIM;
    float acc = bin[c];
    #pragma unroll
    for (int k = 0; k < IN_DIM; ++k) acc += xr[k]*sW[k*HID + c];
    h0[(size_t)node*HID + c] = lrelu(acc, LRELU_S);
}

// ---------------- GAT GEMM: g = h@W, a_dst/a_src per (node, head) ----------------
// 256 threads, NPB=32 nodes/block. Register tile: 4 cols x 4 rows per thread.
// W processed in two 128-col halves (keeps static LDS under 64KB).
// h staged TRANSPOSED (shT[k][j], pad +4) so 4 rows load as one ds_read_b128.
#define NPB 32
#define SHT_LD (NPB + 4)    // pad: kills transpose-write bank conflict, keeps 16B align
__global__ __launch_bounds__(256) void k_gat_gemm(const float* __restrict__ h,
                                                  const float* __restrict__ W,
                                                  const float* __restrict__ att,
                                                  float* __restrict__ g,
                                                  float* __restrict__ adst,
                                                  float* __restrict__ asrc, int n){
    __shared__ float sW[HID*128];        // 32KB: half the W columns
    __shared__ float shT[HID*SHT_LD];    // 9.2KB: h transposed
    __shared__ float satt[HEADS*2*OUTC]; // 2KB
    const int base = blockIdx.x*NPB;

    for (int i = threadIdx.x; i < HEADS*2*OUTC; i += 256) satt[i] = att[i];
    // stage h transposed: lanes read consecutive k (coalesced 256B), write shT[k][j]
    for (int i = threadIdx.x; i < NPB*HID; i += 256){
        int j = i >> 6, k = i & 63;
        float v = (base + j < n) ? h[(size_t)(base + j)*HID + k] : 0.f;
        shT[k*SHT_LD + j] = v;
    }

    const int lane = threadIdx.x & 63;
    const int cg = threadIdx.x & 31;     // col group within half: cols cg*4..+3
    const int rg = threadIdx.x >> 5;     // row group: rows rg*4..+3
    const float4* sW4 = (const float4*)sW;

    for (int half = 0; half < 2; ++half){
        __syncthreads();
        // stage this half of W: rows of 128 floats, coalesced float4
        {
            const float4* W4 = (const float4*)W;
            for (int idx = threadIdx.x; idx < HID*32; idx += 256){
                int k = idx >> 5, cc4 = idx & 31;
                ((float4*)sW)[idx] = W4[k*(GHID/4) + half*32 + cc4];
            }
        }
        __syncthreads();

        float ax[4] = {0,0,0,0}, ay[4] = {0,0,0,0}, az[4] = {0,0,0,0}, aw[4] = {0,0,0,0};
        #pragma unroll 8
        for (int k = 0; k < HID; ++k){
            float4 w = sW4[k*32 + cg];                              // 1 x b128
            float4 hv = *(const float4*)&shT[k*SHT_LD + rg*4];      // 1 x b128 (broadcast)
            float hj[4] = {hv.x, hv.y, hv.z, hv.w};
            #pragma unroll
            for (int j = 0; j < 4; ++j){
                ax[j] += hj[j]*w.x; ay[j] += hj[j]*w.y;
                az[j] += hj[j]*w.z; aw[j] += hj[j]*w.w;
            }
        }

        const int c0 = half*128 + cg*4;
        const int head = c0 >> 6;
        const int o = c0 & 63;
        const float cd0 = satt[head*2*OUTC + o],        cd1 = satt[head*2*OUTC + o + 1];
        const float cd2 = satt[head*2*OUTC + o + 2],    cd3 = satt[head*2*OUTC + o + 3];
        const float cs0 = satt[head*2*OUTC + OUTC + o],     cs1 = satt[head*2*OUTC + OUTC + o + 1];
        const float cs2 = satt[head*2*OUTC + OUTC + o + 2], cs3 = satt[head*2*OUTC + OUTC + o + 3];

        #pragma unroll
        for (int j = 0; j < 4; ++j){
            int row = rg*4 + j;
            bool valid = (base + row) < n;
            if (valid){
                float4 v = make_float4(ax[j], ay[j], az[j], aw[j]);
                *(float4*)&g[(size_t)(base + row)*GHID + c0] = v;
            }
            float pd = ax[j]*cd0 + ay[j]*cd1 + az[j]*cd2 + aw[j]*cd3;
            float ps = ax[j]*cs0 + ay[j]*cs1 + az[j]*cs2 + aw[j]*cs3;
            // reduce over the 16 lanes sharing (head, row-group)
            #pragma unroll
            for (int off = 1; off < 16; off <<= 1){
                pd += __shfl_xor(pd, off, 64);
                ps += __shfl_xor(ps, off, 64);
            }
            if (valid && (lane & 15) == 0){
                adst[(size_t)(base + row)*HEADS + head] = pd;
                asrc[(size_t)(base + row)*HEADS + head] = ps;
            }
        }
    }
}

// ---------------- fused scatter-softmax + aggregate (wave per dst node) ----------------
// Pass 2 chunks edges by 16: lane = (edge-slot, head) computes weights in
// parallel (1 __expf per (edge,head) instead of 64 redundant ones), then the
// serial accumulate reads them via shfl broadcast.
__global__ __launch_bounds__(256) void k_aggr(const float* __restrict__ g,
                                              const float* __restrict__ adst,
                                              const float* __restrict__ asrc,
                                              const int* __restrict__ csr_src,
                                              const int* __restrict__ row_off,
                                              const int* __restrict__ deg,
                                              const float* __restrict__ bg,
                                              float* __restrict__ hout,
                                              int n, int applyLeaky){
    int wid  = (blockIdx.x*256 + threadIdx.x) >> 6;
    int lane = threadIdx.x & 63;
    if (wid >= n) return;
    const int node = wid;
    const int start = row_off[node];
    const int d = deg[node];

    float ad[HEADS], es[HEADS], m[HEADS];
    #pragma unroll
    for (int k = 0; k < HEADS; ++k){
        ad[k] = adst[(size_t)node*HEADS + k];
        es[k] = lrelu(ad[k] + asrc[(size_t)node*HEADS + k], GAT_S);   // self-loop logit
        m[k]  = es[k];
    }
    // pass 1: max over incoming edges (lanes parallel over edges)
    for (int idx = lane; idx < d; idx += 64){
        int s = csr_src[start + idx];
        #pragma unroll
        for (int k = 0; k < HEADS; ++k){
            float e = lrelu(ad[k] + asrc[(size_t)s*HEADS + k], GAT_S);
            m[k] = fmaxf(m[k], e);
        }
    }
    #pragma unroll
    for (int k = 0; k < HEADS; ++k){
        #pragma unroll
        for (int off = 32; off > 0; off >>= 1)
            m[k] = fmaxf(m[k], __shfl_xor(m[k], off, 64));
    }

    // pass 2: self-loop init then chunked accumulate
    float acc[HEADS], den[HEADS];
    #pragma unroll
    for (int k = 0; k < HEADS; ++k){
        float w = __expf(es[k] - m[k]);
        den[k] = w;
        acc[k] = w * g[(size_t)node*GHID + k*OUTC + lane];
    }
    const int eh = lane >> 2;   // edge slot 0..15 within chunk
    const int kh = lane & 3;    // head for the parallel weight computation
    for (int j0 = 0; j0 < d; j0 += 16){
        const int nume = min(16, d - j0);
        int s_mine = 0;
        float wv = 0.f;
        if (eh < nume){
            s_mine = csr_src[start + j0 + eh];
            float e = lrelu(ad[kh] + asrc[(size_t)s_mine*HEADS + kh], GAT_S);
            wv = __expf(e - m[kh]);
        }
        for (int e2 = 0; e2 < nume; ++e2){
            int   s  = __shfl(s_mine, e2*4, 64);
            float w0 = __shfl(wv, e2*4 + 0, 64);
            float w1 = __shfl(wv, e2*4 + 1, 64);
            float w2 = __shfl(wv, e2*4 + 2, 64);
            float w3 = __shfl(wv, e2*4 + 3, 64);
            const float* gr = &g[(size_t)s*GHID];
            acc[0] += w0 * gr[0*OUTC + lane];   // coalesced 256B
            acc[1] += w1 * gr[1*OUTC + lane];
            acc[2] += w2 * gr[2*OUTC + lane];
            acc[3] += w3 * gr[3*OUTC + lane];
            den[0] += w0; den[1] += w1; den[2] += w2; den[3] += w3;
        }
    }
    float o = 0.f;
    #pragma unroll
    for (int k = 0; k < HEADS; ++k) o += acc[k]/den[k];
    o = 0.25f*o + bg[lane];
    if (applyLeaky) o = lrelu(o, LRELU_S);
    hout[(size_t)node*HID + lane] = o;
}

// ---------------- pair scorer ----------------
__global__ __launch_bounds__(256) void k_score(const float* __restrict__ h,
                                               const int* __restrict__ ni,
                                               const int* __restrict__ nj,
                                               const float* __restrict__ Ws1,
                                               const float* __restrict__ bs1,
                                               const float* __restrict__ Ws2,
                                               const float* __restrict__ bs2,
                                               float* __restrict__ out, int P){
    __shared__ float sW1[2*HID*HID];  // 32KB
    __shared__ float sW2[HID];
    for (int i = threadIdx.x; i < 2*HID*HID; i += 256) sW1[i] = Ws1[i];
    if (threadIdx.x < HID) sW2[threadIdx.x] = Ws2[threadIdx.x];
    __syncthreads();
    int wid  = blockIdx.x*4 + (threadIdx.x >> 6);
    int lane = threadIdx.x & 63;
    float b1 = bs1[lane];
    for (int t = 0; t < 4; ++t){
        int p = wid*4 + t;
        if (p >= P) continue;
        int i = ni[p], j = nj[p];
        float hi = h[(size_t)i*HID + lane];
        float hj = h[(size_t)j*HID + lane];
        float acc = b1;
        #pragma unroll
        for (int k = 0; k < HID; ++k) acc += __shfl(hi, k, 64) * sW1[k*HID + lane];
        #pragma unroll
        for (int k = 0; k < HID; ++k) acc += __shfl(hj, k, 64) * sW1[(HID + k)*HID + lane];
        acc = lrelu(acc, LRELU_S);
        float part = acc * sW2[lane];
        #pragma unroll
        for (int off = 32; off > 0; off >>= 1) part += __shfl_xor(part, off, 64);
        if (lane == 0) out[p] = part + bs2[0];
    }
}

extern "C" void kernel_launch(void* const* d_in, const int* in_sizes, int n_in,
                              void* d_out, int out_size, void* d_ws, size_t ws_size,
                              hipStream_t stream) {
    const float* x    = (const float*)d_in[0];
    const int*   ei   = (const int*)  d_in[1];
    const int*   ni   = (const int*)  d_in[2];
    const int*   nj   = (const int*)  d_in[3];
    const float* Win  = (const float*)d_in[4];
    const float* bin  = (const float*)d_in[5];
    const float* Wg0  = (const float*)d_in[6];
    const float* att0 = (const float*)d_in[7];
    const float* bg0  = (const float*)d_in[8];
    const float* Wg1  = (const float*)d_in[9];
    const float* att1 = (const float*)d_in[10];
    const float* bg1  = (const float*)d_in[11];
    const float* Ws1  = (const float*)d_in[12];
    const float* bs1  = (const float*)d_in[13];
    const float* Ws2  = (const float*)d_in[14];
    const float* bs2  = (const float*)d_in[15];
    float* outp = (float*)d_out;

    const int N = in_sizes[0] / IN_DIM;
    const int E = in_sizes[1] / 2;
    const int P = in_sizes[2];
    const int* esrc = ei;
    const int* edst = ei + E;

    // workspace carve-up (256B aligned)
    char* ws = (char*)d_ws;
    size_t off = 0;
    auto carve = [&](size_t bytes) -> void* {
        void* p = ws + off;
        off = (off + bytes + 255) & ~(size_t)255;
        return p;
    };
    int*   deg  = (int*)  carve((size_t)N*4);
    int*   row  = (int*)  carve((size_t)N*4);
    int*   cur  = (int*)  carve((size_t)N*4);
    int*   bsum = (int*)  carve(256*4);
    int*   csr  = (int*)  carve((size_t)E*4);
    float* hA   = (float*)carve((size_t)N*HID*4);
    float* hB   = (float*)carve((size_t)N*HID*4);
    float* g    = (float*)carve((size_t)N*GHID*4);
    float* adt  = (float*)carve((size_t)N*HEADS*4);
    float* asr  = (float*)carve((size_t)N*HEADS*4);
    (void)ws_size; (void)n_in; (void)out_size;

    const int nbN = (N + 255)/256;       // 196 for N=50000
    const int nbE = (E + 255)/256;

    // CSR build (shared by both layers)
    k_zero      <<<nbN, 256, 0, stream>>>(deg, N);
    k_hist      <<<nbE, 256, 0, stream>>>(edst, E, deg);
    k_scan_block<<<nbN, 256, 0, stream>>>(deg, row, bsum, N);
    k_scan_top  <<<1,   256, 0, stream>>>(bsum, nbN);
    k_scan_add  <<<nbN, 256, 0, stream>>>(row, bsum, cur, N);
    k_scatter   <<<nbE, 256, 0, stream>>>(esrc, edst, E, cur, csr);

    // input projection
    k_proj<<<(N*HID + 255)/256, 256, 0, stream>>>(x, Win, bin, hA, N);

    // GAT layer 0
    k_gat_gemm<<<(N + NPB - 1)/NPB, 256, 0, stream>>>(hA, Wg0, att0, g, adt, asr, N);
    k_aggr    <<<(N*64 + 255)/256, 256, 0, stream>>>(g, adt, asr, csr, row, deg, bg0, hB, N, 1);

    // GAT layer 1
    k_gat_gemm<<<(N + NPB - 1)/NPB, 256, 0, stream>>>(hB, Wg1, att1, g, adt, asr, N);
    k_aggr    <<<(N*64 + 255)/256, 256, 0, stream>>>(g, adt, asr, csr, row, deg, bg1, hA, N, 0);

    // pair scorer
    k_score<<<(P + 15)/16, 256, 0, stream>>>(hA, ni, nj, Ws1, bs1, Ws2, bs2, outp, P);
}

// Round 9
// 568.046 us; speedup vs baseline: 1.2495x; 1.2495x over previous
//
#include <hip/hip_runtime.h>
#include <math.h>

#define IN_DIM 32
#define HID 64
#define HEADS 4
#define OUTC 64
#define GHID (HEADS*OUTC)   // 256
#define LRELU_S 0.01f
#define GAT_S 0.2f

__device__ __forceinline__ float lrelu(float v, float s){ return v >= 0.f ? v : s*v; }
// branchless select from a 4-element register array (avoids scratch from dynamic indexing)
__device__ __forceinline__ float sel4(const float a0, const float a1, const float a2, const float a3, int i){
    float rlo = (i & 1) ? a1 : a0;
    float rhi = (i & 1) ? a3 : a2;
    return (i & 2) ? rhi : rlo;
}

// ---------------- CSR build ----------------
__global__ void k_zero(int* __restrict__ p, int n){
    int i = blockIdx.x*256 + threadIdx.x;
    if (i < n) p[i] = 0;
}

__global__ void k_hist(const int* __restrict__ dst, int E, int* __restrict__ deg){
    int i = blockIdx.x*256 + threadIdx.x;
    if (i < E) atomicAdd(&deg[dst[i]], 1);
}

__global__ void k_scan_block(const int* __restrict__ in, int* __restrict__ out,
                             int* __restrict__ bsum, int n){
    __shared__ int s[256];
    int i = blockIdx.x*256 + threadIdx.x;
    int v = (i < n) ? in[i] : 0;
    s[threadIdx.x] = v;
    __syncthreads();
    for (int off = 1; off < 256; off <<= 1){
        int t = (threadIdx.x >= off) ? s[threadIdx.x - off] : 0;
        __syncthreads();
        s[threadIdx.x] += t;
        __syncthreads();
    }
    if (i < n) out[i] = s[threadIdx.x] - v;          // exclusive
    if (threadIdx.x == 255) bsum[blockIdx.x] = s[255];
}

__global__ void k_scan_top(int* __restrict__ bsum, int n){
    __shared__ int s[256];
    int v = (threadIdx.x < n) ? bsum[threadIdx.x] : 0;
    s[threadIdx.x] = v;
    __syncthreads();
    for (int off = 1; off < 256; off <<= 1){
        int t = (threadIdx.x >= off) ? s[threadIdx.x - off] : 0;
        __syncthreads();
        s[threadIdx.x] += t;
        __syncthreads();
    }
    if (threadIdx.x < n) bsum[threadIdx.x] = s[threadIdx.x] - v;  // exclusive
}

__global__ void k_scan_add(int* __restrict__ row, const int* __restrict__ bsum,
                           int* __restrict__ cur, int n){
    int i = blockIdx.x*256 + threadIdx.x;
    if (i < n){
        int v = row[i] + bsum[blockIdx.x];
        row[i] = v;
        cur[i] = v;
    }
}

__global__ void k_scatter(const int* __restrict__ src, const int* __restrict__ dst, int E,
                          int* __restrict__ cur, int* __restrict__ csr_src){
    int i = blockIdx.x*256 + threadIdx.x;
    if (i < E){
        int d = dst[i];
        int pos = atomicAdd(&cur[d], 1);
        csr_src[pos] = src[i];
    }
}

// ---------------- input projection: h0 = leaky(x@W_in + b_in) ----------------
__global__ __launch_bounds__(256) void k_proj(const float* __restrict__ x,
                                              const float* __restrict__ Win,
                                              const float* __restrict__ bin,
                                              float* __restrict__ h0, int n){
    __shared__ float sW[IN_DIM*HID];  // 8KB
    for (int i = threadIdx.x; i < IN_DIM*HID; i += 256) sW[i] = Win[i];
    __syncthreads();
    int gid = blockIdx.x*256 + threadIdx.x;
    int node = gid >> 6, c = gid & 63;
    if (node >= n) return;
    const float* xr = x + (size_t)node*IN_DIM;
    float acc = bin[c];
    #pragma unroll
    for (int k = 0; k < IN_DIM; ++k) acc += xr[k]*sW[k*HID + c];
    h0[(size_t)node*HID + c] = lrelu(acc, LRELU_S);
}

// ---------------- GAT GEMM: g = h@W, a_dst/a_src per (node, head) ----------------
#define NPB 32
#define SHT_LD (NPB + 4)    // pad kills transpose-write bank conflict, keeps 16B align
__global__ __launch_bounds__(256) void k_gat_gemm(const float* __restrict__ h,
                                                  const float* __restrict__ W,
                                                  const float* __restrict__ att,
                                                  float* __restrict__ g,
                                                  float* __restrict__ adst,
                                                  float* __restrict__ asrc, int n){
    __shared__ float sW[HID*128];        // 32KB: half the W columns
    __shared__ float shT[HID*SHT_LD];    // 9.2KB: h transposed
    __shared__ float satt[HEADS*2*OUTC]; // 2KB
    const int base = blockIdx.x*NPB;

    for (int i = threadIdx.x; i < HEADS*2*OUTC; i += 256) satt[i] = att[i];
    for (int i = threadIdx.x; i < NPB*HID; i += 256){
        int j = i >> 6, k = i & 63;
        float v = (base + j < n) ? h[(size_t)(base + j)*HID + k] : 0.f;
        shT[k*SHT_LD + j] = v;
    }

    const int lane = threadIdx.x & 63;
    const int cg = threadIdx.x & 31;     // col group within half: cols cg*4..+3
    const int rg = threadIdx.x >> 5;     // row group: rows rg*4..+3
    const float4* sW4 = (const float4*)sW;

    for (int half = 0; half < 2; ++half){
        __syncthreads();
        {
            const float4* W4 = (const float4*)W;
            for (int idx = threadIdx.x; idx < HID*32; idx += 256){
                int k = idx >> 5, cc4 = idx & 31;
                ((float4*)sW)[idx] = W4[k*(GHID/4) + half*32 + cc4];
            }
        }
        __syncthreads();

        float ax[4] = {0,0,0,0}, ay[4] = {0,0,0,0}, az[4] = {0,0,0,0}, aw[4] = {0,0,0,0};
        #pragma unroll 8
        for (int k = 0; k < HID; ++k){
            float4 w = sW4[k*32 + cg];
            float4 hv = *(const float4*)&shT[k*SHT_LD + rg*4];
            float hj[4] = {hv.x, hv.y, hv.z, hv.w};
            #pragma unroll
            for (int j = 0; j < 4; ++j){
                ax[j] += hj[j]*w.x; ay[j] += hj[j]*w.y;
                az[j] += hj[j]*w.z; aw[j] += hj[j]*w.w;
            }
        }

        const int c0 = half*128 + cg*4;
        const int head = c0 >> 6;
        const int o = c0 & 63;
        const float cd0 = satt[head*2*OUTC + o],        cd1 = satt[head*2*OUTC + o + 1];
        const float cd2 = satt[head*2*OUTC + o + 2],    cd3 = satt[head*2*OUTC + o + 3];
        const float cs0 = satt[head*2*OUTC + OUTC + o],     cs1 = satt[head*2*OUTC + OUTC + o + 1];
        const float cs2 = satt[head*2*OUTC + OUTC + o + 2], cs3 = satt[head*2*OUTC + OUTC + o + 3];

        #pragma unroll
        for (int j = 0; j < 4; ++j){
            int row = rg*4 + j;
            bool valid = (base + row) < n;
            if (valid){
                float4 v = make_float4(ax[j], ay[j], az[j], aw[j]);
                *(float4*)&g[(size_t)(base + row)*GHID + c0] = v;
            }
            float pd = ax[j]*cd0 + ay[j]*cd1 + az[j]*cd2 + aw[j]*cd3;
            float ps = ax[j]*cs0 + ay[j]*cs1 + az[j]*cs2 + aw[j]*cs3;
            #pragma unroll
            for (int off = 1; off < 16; off <<= 1){
                pd += __shfl_xor(pd, off, 64);
                ps += __shfl_xor(ps, off, 64);
            }
            if (valid && (lane & 15) == 0){
                adst[(size_t)(base + row)*HEADS + head] = pd;
                asrc[(size_t)(base + row)*HEADS + head] = ps;
            }
        }
    }
}

// ---------------- fused scatter-softmax + aggregate (wave per dst node) ----------------
// Layout: lane L owns channels 4L..4L+3 (all in head own=L>>4). Serial loop per
// edge: 2 shfl + 1 float4 load + 4 FMA + 1 add. Head-sum at the end via
// shfl_xor(16/32) butterfly; lanes 0..15 write the 64-ch output row as float4.
// Pass 1 uses lrelu monotonicity: max_s lrelu(ad+as) = lrelu(ad + max_s as).
__global__ __launch_bounds__(256) void k_aggr(const float* __restrict__ g,
                                              const float* __restrict__ adst,
                                              const float* __restrict__ asrc,
                                              const int* __restrict__ csr_src,
                                              const int* __restrict__ row_off,
                                              const int* __restrict__ deg,
                                              const float* __restrict__ bg,
                                              float* __restrict__ hout,
                                              int n, int applyLeaky){
    int wid  = (blockIdx.x*256 + threadIdx.x) >> 6;
    int lane = threadIdx.x & 63;
    if (wid >= n) return;
    const int node = wid;
    const int start = row_off[node];
    const int d = deg[node];
    const int own = lane >> 4;          // head owned in accumulate phase

    const float4 as_self = *(const float4*)&asrc[(size_t)node*HEADS];
    const float4 ad4     = *(const float4*)&adst[(size_t)node*HEADS];
    float m0 = as_self.x, m1 = as_self.y, m2 = as_self.z, m3 = as_self.w;

    // pass 1: max over raw asrc of incoming edges (lanes parallel over edges)
    for (int idx = lane; idx < d; idx += 64){
        int s = csr_src[start + idx];
        float4 a4 = *(const float4*)&asrc[(size_t)s*HEADS];
        m0 = fmaxf(m0, a4.x); m1 = fmaxf(m1, a4.y);
        m2 = fmaxf(m2, a4.z); m3 = fmaxf(m3, a4.w);
    }
    #pragma unroll
    for (int off = 32; off > 0; off >>= 1){
        m0 = fmaxf(m0, __shfl_xor(m0, off, 64));
        m1 = fmaxf(m1, __shfl_xor(m1, off, 64));
        m2 = fmaxf(m2, __shfl_xor(m2, off, 64));
        m3 = fmaxf(m3, __shfl_xor(m3, off, 64));
    }
    m0 = lrelu(ad4.x + m0, GAT_S); m1 = lrelu(ad4.y + m1, GAT_S);
    m2 = lrelu(ad4.z + m2, GAT_S); m3 = lrelu(ad4.w + m3, GAT_S);

    // self-loop init (own head only)
    const float ad_own = sel4(ad4.x, ad4.y, ad4.z, ad4.w, own);
    const float as_own = sel4(as_self.x, as_self.y, as_self.z, as_self.w, own);
    const float m_own  = sel4(m0, m1, m2, m3, own);
    float w_self = __expf(lrelu(ad_own + as_own, GAT_S) - m_own);
    float4 gs = *(const float4*)&g[(size_t)node*GHID + 4*lane];
    float a0 = w_self*gs.x, a1 = w_self*gs.y, a2 = w_self*gs.z, a3 = w_self*gs.w;
    float den_own = w_self;

    const int eh = lane >> 2;   // edge slot 0..15 within chunk
    const int kh = lane & 3;    // head for the parallel weight computation
    const float ad_kh = sel4(ad4.x, ad4.y, ad4.z, ad4.w, kh);
    const float m_kh  = sel4(m0, m1, m2, m3, kh);
    for (int j0 = 0; j0 < d; j0 += 16){
        const int nume = min(16, d - j0);
        int s_mine = 0;
        float wv = 0.f;
        if (eh < nume){
            s_mine = csr_src[start + j0 + eh];
            float e = lrelu(ad_kh + asrc[(size_t)s_mine*HEADS + kh], GAT_S);
            wv = __expf(e - m_kh);
        }
        for (int e2 = 0; e2 < nume; ++e2){
            int   s     = __shfl(s_mine, e2*4, 64);
            float w_own = __shfl(wv, e2*4 + own, 64);
            const float4 gv = *(const float4*)&g[(size_t)s*GHID + 4*lane]; // 1KB/wave coalesced
            a0 += w_own*gv.x; a1 += w_own*gv.y;
            a2 += w_own*gv.z; a3 += w_own*gv.w;
            den_own += w_own;
        }
    }

    // per-head normalize, then sum the 4 heads: lanes {L, L^16, L^32, L^48}
    // hold the same output channels for different heads.
    a0 /= den_own; a1 /= den_own; a2 /= den_own; a3 /= den_own;
    #pragma unroll
    for (int off = 16; off <= 32; off <<= 1){
        a0 += __shfl_xor(a0, off, 64);
        a1 += __shfl_xor(a1, off, 64);
        a2 += __shfl_xor(a2, off, 64);
        a3 += __shfl_xor(a3, off, 64);
    }
    if (lane < 16){
        float4 bg4 = *(const float4*)&bg[4*lane];
        float o0 = 0.25f*a0 + bg4.x, o1 = 0.25f*a1 + bg4.y;
        float o2 = 0.25f*a2 + bg4.z, o3 = 0.25f*a3 + bg4.w;
        if (applyLeaky){
            o0 = lrelu(o0, LRELU_S); o1 = lrelu(o1, LRELU_S);
            o2 = lrelu(o2, LRELU_S); o3 = lrelu(o3, LRELU_S);
        }
        *(float4*)&hout[(size_t)node*HID + 4*lane] = make_float4(o0, o1, o2, o3);
    }
}

// ---------------- scorer node-projection: uv = h @ [Ws1_top | Ws1_bot] ----------------
// uv[n][c]       = sum_k h[n][k] * Ws1[k][c]        (u part, c in 0..63)
// uv[n][64 + c]  = sum_k h[n][k] * Ws1[64 + k][c]   (v part)
__global__ __launch_bounds__(256) void k_sproj(const float* __restrict__ h,
                                               const float* __restrict__ Ws1,
                                               float* __restrict__ uv, int n){
    __shared__ float sW[HID*128];     // 32KB: sW[k][half*64 + c] = Ws1[half*64 + k][c]
    __shared__ float shT[HID*SHT_LD]; // 9.2KB
    const int base = blockIdx.x*NPB;

    {
        const float4* W4 = (const float4*)Ws1;
        for (int idx = threadIdx.x; idx < 128*16; idx += 256){
            int r = idx >> 4, c4 = idx & 15;          // r = input-feature row 0..127
            int k = r & 63, half = r >> 6;
            ((float4*)sW)[k*32 + half*16 + c4] = W4[idx];
        }
    }
    for (int i = threadIdx.x; i < NPB*HID; i += 256){
        int j = i >> 6, k = i & 63;
        float v = (base + j < n) ? h[(size_t)(base + j)*HID + k] : 0.f;
        shT[k*SHT_LD + j] = v;
    }
    __syncthreads();

    const int cg = threadIdx.x & 31;     // cols cg*4..+3 of 128
    const int rg = threadIdx.x >> 5;     // rows rg*4..+3
    const float4* sW4 = (const float4*)sW;

    float ax[4] = {0,0,0,0}, ay[4] = {0,0,0,0}, az[4] = {0,0,0,0}, aw[4] = {0,0,0,0};
    #pragma unroll 8
    for (int k = 0; k < HID; ++k){
        float4 w = sW4[k*32 + cg];
        float4 hv = *(const float4*)&shT[k*SHT_LD + rg*4];
        float hj[4] = {hv.x, hv.y, hv.z, hv.w};
        #pragma unroll
        for (int j = 0; j < 4; ++j){
            ax[j] += hj[j]*w.x; ay[j] += hj[j]*w.y;
            az[j] += hj[j]*w.z; aw[j] += hj[j]*w.w;
        }
    }
    #pragma unroll
    for (int j = 0; j < 4; ++j){
        int row = base + rg*4 + j;
        if (row < n){
            float4 v = make_float4(ax[j], ay[j], az[j], aw[j]);
            *(float4*)&uv[(size_t)row*128 + cg*4] = v;
        }
    }
}

// ---------------- pair scorer: out[p] = lrelu(u[i]+v[j]+b1) . Ws2 + b2 ----------------
__global__ __launch_bounds__(256) void k_pair(const float* __restrict__ uv,
                                              const int* __restrict__ ni,
                                              const int* __restrict__ nj,
                                              const float* __restrict__ bs1,
                                              const float* __restrict__ Ws2,
                                              const float* __restrict__ bs2,
                                              float* __restrict__ out, int P){
    const int lane = threadIdx.x & 63;
    const int wid  = blockIdx.x*4 + (threadIdx.x >> 6);
    const float b1 = bs1[lane];
    const float w2 = Ws2[lane];
    const float b2 = bs2[0];
    #pragma unroll
    for (int t = 0; t < 4; ++t){
        int p = wid*4 + t;
        if (p >= P) continue;
        int i = ni[p], j = nj[p];
        float a = uv[(size_t)i*128 + lane];        // u[i]
        float b = uv[(size_t)j*128 + 64 + lane];   // v[j]
        float s = lrelu(a + b + b1, LRELU_S);
        float part = s * w2;
        #pragma unroll
        for (int off = 32; off > 0; off >>= 1) part += __shfl_xor(part, off, 64);
        if (lane == 0) out[p] = part + b2;
    }
}

extern "C" void kernel_launch(void* const* d_in, const int* in_sizes, int n_in,
                              void* d_out, int out_size, void* d_ws, size_t ws_size,
                              hipStream_t stream) {
    const float* x    = (const float*)d_in[0];
    const int*   ei   = (const int*)  d_in[1];
    const int*   ni   = (const int*)  d_in[2];
    const int*   nj   = (const int*)  d_in[3];
    const float* Win  = (const float*)d_in[4];
    const float* bin  = (const float*)d_in[5];
    const float* Wg0  = (const float*)d_in[6];
    const float* att0 = (const float*)d_in[7];
    const float* bg0  = (const float*)d_in[8];
    const float* Wg1  = (const float*)d_in[9];
    const float* att1 = (const float*)d_in[10];
    const float* bg1  = (const float*)d_in[11];
    const float* Ws1  = (const float*)d_in[12];
    const float* bs1  = (const float*)d_in[13];
    const float* Ws2  = (const float*)d_in[14];
    const float* bs2  = (const float*)d_in[15];
    float* outp = (float*)d_out;

    const int N = in_sizes[0] / IN_DIM;
    const int E = in_sizes[1] / 2;
    const int P = in_sizes[2];
    const int* esrc = ei;
    const int* edst = ei + E;

    // workspace carve-up (256B aligned)
    char* ws = (char*)d_ws;
    size_t off = 0;
    auto carve = [&](size_t bytes) -> void* {
        void* p = ws + off;
        off = (off + bytes + 255) & ~(size_t)255;
        return p;
    };
    int*   deg  = (int*)  carve((size_t)N*4);
    int*   row  = (int*)  carve((size_t)N*4);
    int*   cur  = (int*)  carve((size_t)N*4);
    int*   bsum = (int*)  carve(256*4);
    int*   csr  = (int*)  carve((size_t)E*4);
    float* hA   = (float*)carve((size_t)N*HID*4);
    float* hB   = (float*)carve((size_t)N*HID*4);
    float* g    = (float*)carve((size_t)N*GHID*4);
    float* adt  = (float*)carve((size_t)N*HEADS*4);
    float* asr  = (float*)carve((size_t)N*HEADS*4);
    float* uv   = g;   // alias: g is dead after the last k_aggr; uv needs N*128*4 <= N*GHID*4
    (void)ws_size; (void)n_in; (void)out_size;

    const int nbN = (N + 255)/256;
    const int nbE = (E + 255)/256;

    // CSR build (shared by both layers)
    k_zero      <<<nbN, 256, 0, stream>>>(deg, N);
    k_hist      <<<nbE, 256, 0, stream>>>(edst, E, deg);
    k_scan_block<<<nbN, 256, 0, stream>>>(deg, row, bsum, N);
    k_scan_top  <<<1,   256, 0, stream>>>(bsum, nbN);
    k_scan_add  <<<nbN, 256, 0, stream>>>(row, bsum, cur, N);
    k_scatter   <<<nbE, 256, 0, stream>>>(esrc, edst, E, cur, csr);

    // input projection
    k_proj<<<(N*HID + 255)/256, 256, 0, stream>>>(x, Win, bin, hA, N);

    // GAT layer 0
    k_gat_gemm<<<(N + NPB - 1)/NPB, 256, 0, stream>>>(hA, Wg0, att0, g, adt, asr, N);
    k_aggr    <<<(N*64 + 255)/256, 256, 0, stream>>>(g, adt, asr, csr, row, deg, bg0, hB, N, 1);

    // GAT layer 1
    k_gat_gemm<<<(N + NPB - 1)/NPB, 256, 0, stream>>>(hB, Wg1, att1, g, adt, asr, N);
    k_aggr    <<<(N*64 + 255)/256, 256, 0, stream>>>(g, adt, asr, csr, row, deg, bg1, hA, N, 0);

    // pair scorer: per-node projection then cheap per-pair combine
    k_sproj<<<(N + NPB - 1)/NPB, 256, 0, stream>>>(hA, Ws1, uv, N);
    k_pair <<<(P + 15)/16, 256, 0, stream>>>(uv, ni, nj, bs1, Ws2, bs2, outp, P);
}

// Round 10
// 560.669 us; speedup vs baseline: 1.2659x; 1.0132x over previous
//
#include <hip/hip_runtime.h>
#include <math.h>

#define IN_DIM 32
#define HID 64
#define HEADS 4
#define OUTC 64
#define GHID (HEADS*OUTC)   // 256
#define LRELU_S 0.01f
#define GAT_S 0.2f

__device__ __forceinline__ float lrelu(float v, float s){ return v >= 0.f ? v : s*v; }
// branchless select from a 4-element register array (avoids scratch from dynamic indexing)
__device__ __forceinline__ float sel4(const float a0, const float a1, const float a2, const float a3, int i){
    float rlo = (i & 1) ? a1 : a0;
    float rhi = (i & 1) ? a3 : a2;
    return (i & 2) ? rhi : rlo;
}

// ---------------- CSR build ----------------
__global__ void k_zero(int* __restrict__ p, int n){
    int i = blockIdx.x*256 + threadIdx.x;
    if (i < n) p[i] = 0;
}

__global__ void k_hist(const int* __restrict__ dst, int E, int* __restrict__ deg){
    int i = blockIdx.x*256 + threadIdx.x;
    if (i < E) atomicAdd(&deg[dst[i]], 1);
}

__global__ void k_scan_block(const int* __restrict__ in, int* __restrict__ out,
                             int* __restrict__ bsum, int n){
    __shared__ int s[256];
    int i = blockIdx.x*256 + threadIdx.x;
    int v = (i < n) ? in[i] : 0;
    s[threadIdx.x] = v;
    __syncthreads();
    for (int off = 1; off < 256; off <<= 1){
        int t = (threadIdx.x >= off) ? s[threadIdx.x - off] : 0;
        __syncthreads();
        s[threadIdx.x] += t;
        __syncthreads();
    }
    if (i < n) out[i] = s[threadIdx.x] - v;          // exclusive
    if (threadIdx.x == 255) bsum[blockIdx.x] = s[255];
}

__global__ void k_scan_top(int* __restrict__ bsum, int n){
    __shared__ int s[256];
    int v = (threadIdx.x < n) ? bsum[threadIdx.x] : 0;
    s[threadIdx.x] = v;
    __syncthreads();
    for (int off = 1; off < 256; off <<= 1){
        int t = (threadIdx.x >= off) ? s[threadIdx.x - off] : 0;
        __syncthreads();
        s[threadIdx.x] += t;
        __syncthreads();
    }
    if (threadIdx.x < n) bsum[threadIdx.x] = s[threadIdx.x] - v;  // exclusive
}

__global__ void k_scan_add(int* __restrict__ row, const int* __restrict__ bsum,
                           int* __restrict__ cur, int n){
    int i = blockIdx.x*256 + threadIdx.x;
    if (i < n){
        int v = row[i] + bsum[blockIdx.x];
        row[i] = v;
        cur[i] = v;
    }
}

__global__ void k_scatter(const int* __restrict__ src, const int* __restrict__ dst, int E,
                          int* __restrict__ cur, int* __restrict__ csr_src){
    int i = blockIdx.x*256 + threadIdx.x;
    if (i < E){
        int d = dst[i];
        int pos = atomicAdd(&cur[d], 1);
        csr_src[pos] = src[i];
    }
}

// ---------------- input projection: h0 = leaky(x@W_in + b_in) ----------------
__global__ __launch_bounds__(256) void k_proj(const float* __restrict__ x,
                                              const float* __restrict__ Win,
                                              const float* __restrict__ bin,
                                              float* __restrict__ h0, int n){
    __shared__ float sW[IN_DIM*HID];  // 8KB
    for (int i = threadIdx.x; i < IN_DIM*HID; i += 256) sW[i] = Win[i];
    __syncthreads();
    int gid = blockIdx.x*256 + threadIdx.x;
    int node = gid >> 6, c = gid & 63;
    if (node >= n) return;
    const float* xr = x + (size_t)node*IN_DIM;
    float acc = bin[c];
    #pragma unroll
    for (int k = 0; k < IN_DIM; ++k) acc += xr[k]*sW[k*HID + c];
    h0[(size_t)node*HID + c] = lrelu(acc, LRELU_S);
}

// ---------------- GAT GEMM: g = h@W, a_dst/a_src per (node, head) ----------------
#define NPB 32
#define SHT_LD (NPB + 4)    // pad kills transpose-write bank conflict, keeps 16B align
__global__ __launch_bounds__(256) void k_gat_gemm(const float* __restrict__ h,
                                                  const float* __restrict__ W,
                                                  const float* __restrict__ att,
                                                  float* __restrict__ g,
                                                  float* __restrict__ adst,
                                                  float* __restrict__ asrc, int n){
    __shared__ float sW[HID*128];        // 32KB: half the W columns
    __shared__ float shT[HID*SHT_LD];    // 9.2KB: h transposed
    __shared__ float satt[HEADS*2*OUTC]; // 2KB
    const int base = blockIdx.x*NPB;

    for (int i = threadIdx.x; i < HEADS*2*OUTC; i += 256) satt[i] = att[i];
    for (int i = threadIdx.x; i < NPB*HID; i += 256){
        int j = i >> 6, k = i & 63;
        float v = (base + j < n) ? h[(size_t)(base + j)*HID + k] : 0.f;
        shT[k*SHT_LD + j] = v;
    }

    const int lane = threadIdx.x & 63;
    const int cg = threadIdx.x & 31;     // col group within half: cols cg*4..+3
    const int rg = threadIdx.x >> 5;     // row group: rows rg*4..+3
    const float4* sW4 = (const float4*)sW;

    for (int half = 0; half < 2; ++half){
        __syncthreads();
        {
            const float4* W4 = (const float4*)W;
            for (int idx = threadIdx.x; idx < HID*32; idx += 256){
                int k = idx >> 5, cc4 = idx & 31;
                ((float4*)sW)[idx] = W4[k*(GHID/4) + half*32 + cc4];
            }
        }
        __syncthreads();

        float ax[4] = {0,0,0,0}, ay[4] = {0,0,0,0}, az[4] = {0,0,0,0}, aw[4] = {0,0,0,0};
        #pragma unroll 8
        for (int k = 0; k < HID; ++k){
            float4 w = sW4[k*32 + cg];
            float4 hv = *(const float4*)&shT[k*SHT_LD + rg*4];
            float hj[4] = {hv.x, hv.y, hv.z, hv.w};
            #pragma unroll
            for (int j = 0; j < 4; ++j){
                ax[j] += hj[j]*w.x; ay[j] += hj[j]*w.y;
                az[j] += hj[j]*w.z; aw[j] += hj[j]*w.w;
            }
        }

        const int c0 = half*128 + cg*4;
        const int head = c0 >> 6;
        const int o = c0 & 63;
        const float cd0 = satt[head*2*OUTC + o],        cd1 = satt[head*2*OUTC + o + 1];
        const float cd2 = satt[head*2*OUTC + o + 2],    cd3 = satt[head*2*OUTC + o + 3];
        const float cs0 = satt[head*2*OUTC + OUTC + o],     cs1 = satt[head*2*OUTC + OUTC + o + 1];
        const float cs2 = satt[head*2*OUTC + OUTC + o + 2], cs3 = satt[head*2*OUTC + OUTC + o + 3];

        #pragma unroll
        for (int j = 0; j < 4; ++j){
            int row = rg*4 + j;
            bool valid = (base + row) < n;
            if (valid){
                float4 v = make_float4(ax[j], ay[j], az[j], aw[j]);
                *(float4*)&g[(size_t)(base + row)*GHID + c0] = v;
            }
            float pd = ax[j]*cd0 + ay[j]*cd1 + az[j]*cd2 + aw[j]*cd3;
            float ps = ax[j]*cs0 + ay[j]*cs1 + az[j]*cs2 + aw[j]*cs3;
            #pragma unroll
            for (int off = 1; off < 16; off <<= 1){
                pd += __shfl_xor(pd, off, 64);
                ps += __shfl_xor(ps, off, 64);
            }
            if (valid && (lane & 15) == 0){
                adst[(size_t)(base + row)*HEADS + head] = pd;
                asrc[(size_t)(base + row)*HEADS + head] = ps;
            }
        }
    }
}

// ---------------- fused scatter-softmax + aggregate (wave per dst node) ----------------
// Lane L owns channels 4L..4L+3 (head own=L>>4). Pass-2 serial loop is 4-deep
// load-batched: 4 independent float4 gathers in flight (MLP=4) then 16 FMA.
// Pass 1 uses lrelu monotonicity: max_s lrelu(ad+as) = lrelu(ad + max_s as).
__global__ __launch_bounds__(256) void k_aggr(const float* __restrict__ g,
                                              const float* __restrict__ adst,
                                              const float* __restrict__ asrc,
                                              const int* __restrict__ csr_src,
                                              const int* __restrict__ row_off,
                                              const int* __restrict__ deg,
                                              const float* __restrict__ bg,
                                              float* __restrict__ hout,
                                              int n, int applyLeaky){
    int wid  = (blockIdx.x*256 + threadIdx.x) >> 6;
    int lane = threadIdx.x & 63;
    if (wid >= n) return;
    const int node = wid;
    const int start = row_off[node];
    const int d = deg[node];
    const int own = lane >> 4;          // head owned in accumulate phase

    const float4 as_self = *(const float4*)&asrc[(size_t)node*HEADS];
    const float4 ad4     = *(const float4*)&adst[(size_t)node*HEADS];
    float m0 = as_self.x, m1 = as_self.y, m2 = as_self.z, m3 = as_self.w;

    // pass 1: max over raw asrc of incoming edges (lanes parallel over edges)
    for (int idx = lane; idx < d; idx += 64){
        int s = csr_src[start + idx];
        float4 a4 = *(const float4*)&asrc[(size_t)s*HEADS];
        m0 = fmaxf(m0, a4.x); m1 = fmaxf(m1, a4.y);
        m2 = fmaxf(m2, a4.z); m3 = fmaxf(m3, a4.w);
    }
    #pragma unroll
    for (int off = 32; off > 0; off >>= 1){
        m0 = fmaxf(m0, __shfl_xor(m0, off, 64));
        m1 = fmaxf(m1, __shfl_xor(m1, off, 64));
        m2 = fmaxf(m2, __shfl_xor(m2, off, 64));
        m3 = fmaxf(m3, __shfl_xor(m3, off, 64));
    }
    m0 = lrelu(ad4.x + m0, GAT_S); m1 = lrelu(ad4.y + m1, GAT_S);
    m2 = lrelu(ad4.z + m2, GAT_S); m3 = lrelu(ad4.w + m3, GAT_S);

    // self-loop init (own head only)
    const float ad_own = sel4(ad4.x, ad4.y, ad4.z, ad4.w, own);
    const float as_own = sel4(as_self.x, as_self.y, as_self.z, as_self.w, own);
    const float m_own  = sel4(m0, m1, m2, m3, own);
    float w_self = __expf(lrelu(ad_own + as_own, GAT_S) - m_own);
    float4 gs = *(const float4*)&g[(size_t)node*GHID + 4*lane];
    float a0 = w_self*gs.x, a1 = w_self*gs.y, a2 = w_self*gs.z, a3 = w_self*gs.w;
    float den_own = w_self;

    const int eh = lane >> 2;   // edge slot 0..15 within chunk
    const int kh = lane & 3;    // head for the parallel weight computation
    const float ad_kh = sel4(ad4.x, ad4.y, ad4.z, ad4.w, kh);
    const float m_kh  = sel4(m0, m1, m2, m3, kh);
    for (int j0 = 0; j0 < d; j0 += 16){
        const int nume = min(16, d - j0);
        int s_mine = 0;
        float wv = 0.f;
        if (eh < nume){
            s_mine = csr_src[start + j0 + eh];
            float e = lrelu(ad_kh + asrc[(size_t)s_mine*HEADS + kh], GAT_S);
            wv = __expf(e - m_kh);
        }
        int e2 = 0;
        // 4-deep batched: 4 independent gathers in flight, then 16 FMA
        for (; e2 + 4 <= nume; e2 += 4){
            int sA = __shfl(s_mine, (e2+0)*4, 64);
            int sB = __shfl(s_mine, (e2+1)*4, 64);
            int sC = __shfl(s_mine, (e2+2)*4, 64);
            int sD = __shfl(s_mine, (e2+3)*4, 64);
            float wA = __shfl(wv, (e2+0)*4 + own, 64);
            float wB = __shfl(wv, (e2+1)*4 + own, 64);
            float wC = __shfl(wv, (e2+2)*4 + own, 64);
            float wD = __shfl(wv, (e2+3)*4 + own, 64);
            const float4 gA = *(const float4*)&g[(size_t)sA*GHID + 4*lane];
            const float4 gB = *(const float4*)&g[(size_t)sB*GHID + 4*lane];
            const float4 gC = *(const float4*)&g[(size_t)sC*GHID + 4*lane];
            const float4 gD = *(const float4*)&g[(size_t)sD*GHID + 4*lane];
            a0 += wA*gA.x; a1 += wA*gA.y; a2 += wA*gA.z; a3 += wA*gA.w;
            a0 += wB*gB.x; a1 += wB*gB.y; a2 += wB*gB.z; a3 += wB*gB.w;
            a0 += wC*gC.x; a1 += wC*gC.y; a2 += wC*gC.z; a3 += wC*gC.w;
            a0 += wD*gD.x; a1 += wD*gD.y; a2 += wD*gD.z; a3 += wD*gD.w;
            den_own += (wA + wB) + (wC + wD);
        }
        for (; e2 < nume; ++e2){
            int   s     = __shfl(s_mine, e2*4, 64);
            float w_own = __shfl(wv, e2*4 + own, 64);
            const float4 gv = *(const float4*)&g[(size_t)s*GHID + 4*lane];
            a0 += w_own*gv.x; a1 += w_own*gv.y;
            a2 += w_own*gv.z; a3 += w_own*gv.w;
            den_own += w_own;
        }
    }

    // per-head normalize, then sum the 4 heads: lanes {L, L^16, L^32, L^48}
    // hold the same output channels for different heads.
    a0 /= den_own; a1 /= den_own; a2 /= den_own; a3 /= den_own;
    #pragma unroll
    for (int off = 16; off <= 32; off <<= 1){
        a0 += __shfl_xor(a0, off, 64);
        a1 += __shfl_xor(a1, off, 64);
        a2 += __shfl_xor(a2, off, 64);
        a3 += __shfl_xor(a3, off, 64);
    }
    if (lane < 16){
        float4 bg4 = *(const float4*)&bg[4*lane];
        float o0 = 0.25f*a0 + bg4.x, o1 = 0.25f*a1 + bg4.y;
        float o2 = 0.25f*a2 + bg4.z, o3 = 0.25f*a3 + bg4.w;
        if (applyLeaky){
            o0 = lrelu(o0, LRELU_S); o1 = lrelu(o1, LRELU_S);
            o2 = lrelu(o2, LRELU_S); o3 = lrelu(o3, LRELU_S);
        }
        *(float4*)&hout[(size_t)node*HID + 4*lane] = make_float4(o0, o1, o2, o3);
    }
}

// ---------------- scorer node-projection: uv = h @ [Ws1_top | Ws1_bot] ----------------
// uv[n][c]       = sum_k h[n][k] * Ws1[k][c]        (u part, c in 0..63)
// uv[n][64 + c]  = sum_k h[n][k] * Ws1[64 + k][c]   (v part)
__global__ __launch_bounds__(256) void k_sproj(const float* __restrict__ h,
                                               const float* __restrict__ Ws1,
                                               float* __restrict__ uv, int n){
    __shared__ float sW[HID*128];     // 32KB: sW[k][half*64 + c] = Ws1[half*64 + k][c]
    __shared__ float shT[HID*SHT_LD]; // 9.2KB
    const int base = blockIdx.x*NPB;

    {
        const float4* W4 = (const float4*)Ws1;
        for (int idx = threadIdx.x; idx < 128*16; idx += 256){
            int r = idx >> 4, c4 = idx & 15;          // r = input-feature row 0..127
            int k = r & 63, half = r >> 6;
            ((float4*)sW)[k*32 + half*16 + c4] = W4[idx];
        }
    }
    for (int i = threadIdx.x; i < NPB*HID; i += 256){
        int j = i >> 6, k = i & 63;
        float v = (base + j < n) ? h[(size_t)(base + j)*HID + k] : 0.f;
        shT[k*SHT_LD + j] = v;
    }
    __syncthreads();

    const int cg = threadIdx.x & 31;     // cols cg*4..+3 of 128
    const int rg = threadIdx.x >> 5;     // rows rg*4..+3
    const float4* sW4 = (const float4*)sW;

    float ax[4] = {0,0,0,0}, ay[4] = {0,0,0,0}, az[4] = {0,0,0,0}, aw[4] = {0,0,0,0};
    #pragma unroll 8
    for (int k = 0; k < HID; ++k){
        float4 w = sW4[k*32 + cg];
        float4 hv = *(const float4*)&shT[k*SHT_LD + rg*4];
        float hj[4] = {hv.x, hv.y, hv.z, hv.w};
        #pragma unroll
        for (int j = 0; j < 4; ++j){
            ax[j] += hj[j]*w.x; ay[j] += hj[j]*w.y;
            az[j] += hj[j]*w.z; aw[j] += hj[j]*w.w;
        }
    }
    #pragma unroll
    for (int j = 0; j < 4; ++j){
        int row = base + rg*4 + j;
        if (row < n){
            float4 v = make_float4(ax[j], ay[j], az[j], aw[j]);
            *(float4*)&uv[(size_t)row*128 + cg*4] = v;
        }
    }
}

// ---------------- pair scorer: out[p] = lrelu(u[i]+v[j]+b1) . Ws2 + b2 ----------------
__global__ __launch_bounds__(256) void k_pair(const float* __restrict__ uv,
                                              const int* __restrict__ ni,
                                              const int* __restrict__ nj,
                                              const float* __restrict__ bs1,
                                              const float* __restrict__ Ws2,
                                              const float* __restrict__ bs2,
                                              float* __restrict__ out, int P){
    const int lane = threadIdx.x & 63;
    const int wid  = blockIdx.x*4 + (threadIdx.x >> 6);
    const float b1 = bs1[lane];
    const float w2 = Ws2[lane];
    const float b2 = bs2[0];
    #pragma unroll
    for (int t = 0; t < 4; ++t){
        int p = wid*4 + t;
        if (p >= P) continue;
        int i = ni[p], j = nj[p];
        float a = uv[(size_t)i*128 + lane];        // u[i]
        float b = uv[(size_t)j*128 + 64 + lane];   // v[j]
        float s = lrelu(a + b + b1, LRELU_S);
        float part = s * w2;
        #pragma unroll
        for (int off = 32; off > 0; off >>= 1) part += __shfl_xor(part, off, 64);
        if (lane == 0) out[p] = part + b2;
    }
}

extern "C" void kernel_launch(void* const* d_in, const int* in_sizes, int n_in,
                              void* d_out, int out_size, void* d_ws, size_t ws_size,
                              hipStream_t stream) {
    const float* x    = (const float*)d_in[0];
    const int*   ei   = (const int*)  d_in[1];
    const int*   ni   = (const int*)  d_in[2];
    const int*   nj   = (const int*)  d_in[3];
    const float* Win  = (const float*)d_in[4];
    const float* bin  = (const float*)d_in[5];
    const float* Wg0  = (const float*)d_in[6];
    const float* att0 = (const float*)d_in[7];
    const float* bg0  = (const float*)d_in[8];
    const float* Wg1  = (const float*)d_in[9];
    const float* att1 = (const float*)d_in[10];
    const float* bg1  = (const float*)d_in[11];
    const float* Ws1  = (const float*)d_in[12];
    const float* bs1  = (const float*)d_in[13];
    const float* Ws2  = (const float*)d_in[14];
    const float* bs2  = (const float*)d_in[15];
    float* outp = (float*)d_out;

    const int N = in_sizes[0] / IN_DIM;
    const int E = in_sizes[1] / 2;
    const int P = in_sizes[2];
    const int* esrc = ei;
    const int* edst = ei + E;

    // workspace carve-up (256B aligned)
    char* ws = (char*)d_ws;
    size_t off = 0;
    auto carve = [&](size_t bytes) -> void* {
        void* p = ws + off;
        off = (off + bytes + 255) & ~(size_t)255;
        return p;
    };
    int*   deg  = (int*)  carve((size_t)N*4);
    int*   row  = (int*)  carve((size_t)N*4);
    int*   cur  = (int*)  carve((size_t)N*4);
    int*   bsum = (int*)  carve(256*4);
    int*   csr  = (int*)  carve((size_t)E*4);
    float* hA   = (float*)carve((size_t)N*HID*4);
    float* hB   = (float*)carve((size_t)N*HID*4);
    float* g    = (float*)carve((size_t)N*GHID*4);
    float* adt  = (float*)carve((size_t)N*HEADS*4);
    float* asr  = (float*)carve((size_t)N*HEADS*4);
    float* uv   = g;   // alias: g is dead after the last k_aggr; uv needs N*128*4 <= N*GHID*4
    (void)ws_size; (void)n_in; (void)out_size;

    const int nbN = (N + 255)/256;
    const int nbE = (E + 255)/256;

    // CSR build (shared by both layers)
    k_zero      <<<nbN, 256, 0, stream>>>(deg, N);
    k_hist      <<<nbE, 256, 0, stream>>>(edst, E, deg);
    k_scan_block<<<nbN, 256, 0, stream>>>(deg, row, bsum, N);
    k_scan_top  <<<1,   256, 0, stream>>>(bsum, nbN);
    k_scan_add  <<<nbN, 256, 0, stream>>>(row, bsum, cur, N);
    k_scatter   <<<nbE, 256, 0, stream>>>(esrc, edst, E, cur, csr);

    // input projection
    k_proj<<<(N*HID + 255)/256, 256, 0, stream>>>(x, Win, bin, hA, N);

    // GAT layer 0
    k_gat_gemm<<<(N + NPB - 1)/NPB, 256, 0, stream>>>(hA, Wg0, att0, g, adt, asr, N);
    k_aggr    <<<(N*64 + 255)/256, 256, 0, stream>>>(g, adt, asr, csr, row, deg, bg0, hB, N, 1);

    // GAT layer 1
    k_gat_gemm<<<(N + NPB - 1)/NPB, 256, 0, stream>>>(hB, Wg1, att1, g, adt, asr, N);
    k_aggr    <<<(N*64 + 255)/256, 256, 0, stream>>>(g, adt, asr, csr, row, deg, bg1, hA, N, 0);

    // pair scorer: per-node projection then cheap per-pair combine
    k_sproj<<<(N + NPB - 1)/NPB, 256, 0, stream>>>(hA, Ws1, uv, N);
    k_pair <<<(P + 15)/16, 256, 0, stream>>>(uv, ni, nj, bs1, Ws2, bs2, outp, P);
}